// Round 1
// baseline (312.245 us; speedup 1.0000x reference)
//
#include <hip/hip_runtime.h>

#define EMBED 1024
#define HEAD 64
#define NB 4
#define SEQ 4096

typedef __attribute__((ext_vector_type(8))) short short8;
typedef __attribute__((ext_vector_type(4))) float f32x4;

union S8u { short8 v; uint u[4]; ushort s[8]; };

__device__ __forceinline__ ushort f2bf(float f) {
  union { float f; uint u; } x; x.f = f;
  uint u = x.u;
  return (ushort)((u + 0x7fffu + ((u >> 16) & 1u)) >> 16);
}

// ---------------- kernel 1: transpose weights to bf16 wT[t][c][k] ----------------
__global__ __launch_bounds__(256) void prep_w(const float* __restrict__ wq,
                                              const float* __restrict__ wk,
                                              const float* __restrict__ wv,
                                              ushort* __restrict__ wT) {
  int idx = blockIdx.x * 256 + threadIdx.x;
  if (idx >= 3 * HEAD * EMBED) return;
  int t = idx >> 16;            // HEAD*EMBED = 65536
  int rem = idx & 0xFFFF;
  int c = rem >> 10;
  int k = rem & 1023;
  const float* w = (t == 0) ? wq : (t == 1) ? wk : wv;
  wT[idx] = f2bf(w[k * HEAD + c]);
}

// ---------------- kernel 2: projections -> q_bf16 (scaled 1/8), k_bf16, v^T bf16 --
__global__ __launch_bounds__(256) void proj_kernel(
    const float* __restrict__ qsrc, const float* __restrict__ ksrc,
    const float* __restrict__ vsrc, const ushort* __restrict__ wT,
    ushort* __restrict__ qb, ushort* __restrict__ kb, ushort* __restrict__ vt) {
  int t = blockIdx.y;
  const float* src = (t == 0) ? qsrc : (t == 1) ? ksrc : vsrc;
  const ushort* wt = wT + t * (HEAD * EMBED);
  int lane = threadIdx.x & 63;
  int wid = threadIdx.x >> 6;
  int c = lane & 15;
  int g = lane >> 4;
  int arow_i = blockIdx.x * 64 + wid * 16 + c;   // A row for MFMA: lane&15
  const float* arow = src + (size_t)arow_i * EMBED;

  f32x4 acc[4];
#pragma unroll
  for (int i = 0; i < 4; ++i) acc[i] = {0.f, 0.f, 0.f, 0.f};

  for (int k0 = 0; k0 < EMBED; k0 += 32) {
    // A fragment: halves at k0+4g and k0+16+4g (same slot mapping used for B)
    float4 a0 = *(const float4*)(arow + k0 + 4 * g);
    float4 a1 = *(const float4*)(arow + k0 + 16 + 4 * g);
    S8u a;
    a.s[0] = f2bf(a0.x); a.s[1] = f2bf(a0.y); a.s[2] = f2bf(a0.z); a.s[3] = f2bf(a0.w);
    a.s[4] = f2bf(a1.x); a.s[5] = f2bf(a1.y); a.s[6] = f2bf(a1.z); a.s[7] = f2bf(a1.w);
#pragma unroll
    for (int nf = 0; nf < 4; ++nf) {
      const ushort* wrow = wt + (size_t)(nf * 16 + c) * EMBED + k0 + 4 * g;
      uint2 lo = *(const uint2*)(wrow);
      uint2 hi = *(const uint2*)(wrow + 16);
      S8u b; b.u[0] = lo.x; b.u[1] = lo.y; b.u[2] = hi.x; b.u[3] = hi.y;
      acc[nf] = __builtin_amdgcn_mfma_f32_16x16x32_bf16(a.v, b.v, acc[nf], 0, 0, 0);
    }
  }

  // epilogue: C/D layout col=lane&15, row=4*(lane>>4)+reg  (m89-verified)
  int row_base = blockIdx.x * 64 + wid * 16 + 4 * g;
#pragma unroll
  for (int nf = 0; nf < 4; ++nf) {
#pragma unroll
    for (int r = 0; r < 4; ++r) {
      int row = row_base + r;
      int col = nf * 16 + c;
      float val = acc[nf][r];
      if (t == 0) {
        qb[(size_t)row * HEAD + col] = f2bf(val * 0.125f);  // fold 1/sqrt(64)
      } else if (t == 1) {
        kb[(size_t)row * HEAD + col] = f2bf(val);
      } else {
        int bb = row >> 12;
        int s = row & (SEQ - 1);
        vt[((size_t)(bb * HEAD + col) << 12) + s] = f2bf(val);  // store V transposed
      }
    }
  }
}

// ---------------- kernel 3: causal flash attention, 1 wave / 16 q-rows ----------
__global__ __launch_bounds__(64) void flash_kernel(
    const ushort* __restrict__ qb, const ushort* __restrict__ kb,
    const ushort* __restrict__ vt, float* __restrict__ out) {
  __shared__ ushort P_lds[16][64];
  int lane = threadIdx.x;
  int c = lane & 15;
  int g = lane >> 4;
  int bidx = blockIdx.x;
  int b = bidx & 3;
  int qt = 255 - (bidx >> 2);   // longest tiles first (LPT balance)
  int q0 = qt * 16;

  // Q fragments (rows = lane&15), q already scaled by 1/8
  const ushort* qrow = qb + (size_t)(b * SEQ + q0 + c) * HEAD + 4 * g;
  short8 qa[2];
#pragma unroll
  for (int s = 0; s < 2; ++s) {
    uint2 lo = *(const uint2*)(qrow + 32 * s);
    uint2 hi = *(const uint2*)(qrow + 32 * s + 16);
    S8u tt; tt.u[0] = lo.x; tt.u[1] = lo.y; tt.u[2] = hi.x; tt.u[3] = hi.y;
    qa[s] = tt.v;
  }

  f32x4 O[4];
#pragma unroll
  for (int i = 0; i < 4; ++i) O[i] = {0.f, 0.f, 0.f, 0.f};
  float m[4] = {-1e30f, -1e30f, -1e30f, -1e30f};
  float l[4] = {0.f, 0.f, 0.f, 0.f};

  const ushort* kbb = kb + (size_t)b * SEQ * HEAD;
  const ushort* vtb = vt + (size_t)b * HEAD * SEQ;

  int nkt = ((q0 + 15) >> 6) + 1;   // 64-key tiles that intersect the causal band
  for (int kt = 0; kt < nkt; ++kt) {
    int k0 = kt << 6;

    // ---- S = Q K^T  (16 x 64) ----
    f32x4 Sf[4];
#pragma unroll
    for (int i = 0; i < 4; ++i) Sf[i] = {0.f, 0.f, 0.f, 0.f};
#pragma unroll
    for (int nf = 0; nf < 4; ++nf) {
      const ushort* krow = kbb + (size_t)(k0 + nf * 16 + c) * HEAD + 4 * g;
#pragma unroll
      for (int s = 0; s < 2; ++s) {
        uint2 lo = *(const uint2*)(krow + 32 * s);
        uint2 hi = *(const uint2*)(krow + 32 * s + 16);
        S8u tt; tt.u[0] = lo.x; tt.u[1] = lo.y; tt.u[2] = hi.x; tt.u[3] = hi.y;
        Sf[nf] = __builtin_amdgcn_mfma_f32_16x16x32_bf16(qa[s], tt.v, Sf[nf], 0, 0, 0);
      }
    }

    // ---- causal mask (only tiles crossing the diagonal) ----
    if (k0 + 63 > q0) {
#pragma unroll
      for (int nf = 0; nf < 4; ++nf)
#pragma unroll
        for (int r = 0; r < 4; ++r) {
          int key = k0 + nf * 16 + c;
          int qr = q0 + 4 * g + r;
          if (key > qr) Sf[nf][r] = -1e30f;
        }
    }

    // ---- online softmax ----
    float rm[4], rs[4];
#pragma unroll
    for (int r = 0; r < 4; ++r)
      rm[r] = fmaxf(fmaxf(Sf[0][r], Sf[1][r]), fmaxf(Sf[2][r], Sf[3][r]));
#pragma unroll
    for (int off = 1; off < 16; off <<= 1)
#pragma unroll
      for (int r = 0; r < 4; ++r)
        rm[r] = fmaxf(rm[r], __shfl_xor(rm[r], off, 16));
    float alpha[4];
#pragma unroll
    for (int r = 0; r < 4; ++r) {
      float mn = fmaxf(m[r], rm[r]);
      alpha[r] = __expf(m[r] - mn);
      m[r] = mn;
    }
#pragma unroll
    for (int nf = 0; nf < 4; ++nf)
#pragma unroll
      for (int r = 0; r < 4; ++r)
        Sf[nf][r] = __expf(Sf[nf][r] - m[r]);
#pragma unroll
    for (int r = 0; r < 4; ++r)
      rs[r] = (Sf[0][r] + Sf[1][r]) + (Sf[2][r] + Sf[3][r]);
#pragma unroll
    for (int off = 1; off < 16; off <<= 1)
#pragma unroll
      for (int r = 0; r < 4; ++r)
        rs[r] += __shfl_xor(rs[r], off, 16);
#pragma unroll
    for (int r = 0; r < 4; ++r)
      l[r] = l[r] * alpha[r] + rs[r];
#pragma unroll
    for (int nf = 0; nf < 4; ++nf)
#pragma unroll
      for (int r = 0; r < 4; ++r)
        O[nf][r] *= alpha[r];

    // ---- P -> bf16 via LDS (C-layout write, A-layout read) ----
#pragma unroll
    for (int nf = 0; nf < 4; ++nf)
#pragma unroll
      for (int r = 0; r < 4; ++r)
        P_lds[4 * g + r][nf * 16 + c] = f2bf(Sf[nf][r]);
    __syncthreads();

    // ---- O += P V  (V^T stored so B-fragments are contiguous) ----
#pragma unroll
    for (int ks = 0; ks < 2; ++ks) {
      const ushort* prow = &P_lds[c][ks * 32 + 4 * g];
      uint2 plo = *(const uint2*)prow;
      uint2 phi = *(const uint2*)(prow + 16);
      S8u pa; pa.u[0] = plo.x; pa.u[1] = plo.y; pa.u[2] = phi.x; pa.u[3] = phi.y;
#pragma unroll
      for (int nf = 0; nf < 4; ++nf) {
        const ushort* vrow = vtb + (size_t)(nf * 16 + c) * SEQ + k0 + ks * 32 + 4 * g;
        uint2 vlo = *(const uint2*)vrow;
        uint2 vhi = *(const uint2*)(vrow + 16);
        S8u vb; vb.u[0] = vlo.x; vb.u[1] = vlo.y; vb.u[2] = vhi.x; vb.u[3] = vhi.y;
        O[nf] = __builtin_amdgcn_mfma_f32_16x16x32_bf16(pa.v, vb.v, O[nf], 0, 0, 0);
      }
    }
    __syncthreads();
  }

  // ---- epilogue ----
#pragma unroll
  for (int r = 0; r < 4; ++r) {
    float inv = 1.0f / l[r];
#pragma unroll
    for (int nf = 0; nf < 4; ++nf)
      out[(size_t)(b * SEQ + q0 + 4 * g + r) * HEAD + nf * 16 + c] = O[nf][r] * inv;
  }
}

extern "C" void kernel_launch(void* const* d_in, const int* in_sizes, int n_in,
                              void* d_out, int out_size, void* d_ws, size_t ws_size,
                              hipStream_t stream) {
  const float* qsrc = (const float*)d_in[0];
  const float* ksrc = (const float*)d_in[1];
  const float* vsrc = (const float*)d_in[2];
  const float* wq = (const float*)d_in[3];
  const float* wk = (const float*)d_in[4];
  const float* wv = (const float*)d_in[5];
  float* out = (float*)d_out;

  char* ws = (char*)d_ws;
  ushort* wT = (ushort*)ws;                       // 3*64*1024*2   = 384 KB
  ushort* qb = (ushort*)(ws + 393216);            // 16384*64*2    = 2 MB
  ushort* kb = (ushort*)(ws + 393216 + 2097152);  // 2 MB
  ushort* vt = (ushort*)(ws + 393216 + 2 * 2097152);  // 2 MB (transposed V)

  prep_w<<<dim3(768), dim3(256), 0, stream>>>(wq, wk, wv, wT);
  proj_kernel<<<dim3(256, 3), dim3(256), 0, stream>>>(qsrc, ksrc, vsrc, wT, qb, kb, vt);
  flash_kernel<<<dim3(1024), dim3(64), 0, stream>>>(qb, kb, vt, out);
}

// Round 2
// 183.745 us; speedup vs baseline: 1.6993x; 1.6993x over previous
//
#include <hip/hip_runtime.h>

#define EMBED 1024
#define HEAD 64
#define SEQ 4096

typedef __attribute__((ext_vector_type(8))) short short8;
typedef __attribute__((ext_vector_type(4))) float f32x4;

union S8u { short8 v; uint u[4]; ushort s[8]; };

__device__ __forceinline__ ushort f2bf(float f) {
  union { float f; uint u; } x; x.f = f;
  return (ushort)((x.u + 0x7fffu + ((x.u >> 16) & 1u)) >> 16);
}

__device__ __forceinline__ short8 ld16(const ushort* p) {
  uint4 q = *(const uint4*)p;
  S8u t; t.u[0] = q.x; t.u[1] = q.y; t.u[2] = q.z; t.u[3] = q.w;
  return t.v;
}

// ---------------- kernel 1: transpose weights to bf16 wT[t][c][k] ----------------
__global__ __launch_bounds__(256) void prep_w(const float* __restrict__ wq,
                                              const float* __restrict__ wk,
                                              const float* __restrict__ wv,
                                              ushort* __restrict__ wT) {
  int idx = blockIdx.x * 256 + threadIdx.x;
  if (idx >= 3 * HEAD * EMBED) return;
  int t = idx >> 16;            // HEAD*EMBED = 65536
  int rem = idx & 0xFFFF;
  int c = rem >> 10;
  int k = rem & 1023;
  const float* w = (t == 0) ? wq : (t == 1) ? wk : wv;
  wT[idx] = f2bf(w[k * HEAD + c]);
}

// ---------------- kernel 2: projections -> q_bf16 (scaled 1/8), k_bf16, v^T bf16 --
__global__ __launch_bounds__(256) void proj_kernel(
    const float* __restrict__ qsrc, const float* __restrict__ ksrc,
    const float* __restrict__ vsrc, const ushort* __restrict__ wT,
    ushort* __restrict__ qb, ushort* __restrict__ kb, ushort* __restrict__ vt) {
  int t = blockIdx.y;
  const float* src = (t == 0) ? qsrc : (t == 1) ? ksrc : vsrc;
  const ushort* wt = wT + t * (HEAD * EMBED);
  int lane = threadIdx.x & 63;
  int wid = threadIdx.x >> 6;
  int c = lane & 15;
  int g = lane >> 4;
  int arow_i = blockIdx.x * 64 + wid * 16 + c;   // A row (lane&15)
  const float* arow = src + (size_t)arow_i * EMBED;

  f32x4 acc[4];
#pragma unroll
  for (int i = 0; i < 4; ++i) acc[i] = {0.f, 0.f, 0.f, 0.f};

#pragma unroll 4
  for (int k0 = 0; k0 < EMBED; k0 += 32) {
    // contiguous-8 slot mapping: slot s <-> k0 + 8g + s (same for A and B)
    float4 a0 = *(const float4*)(arow + k0 + 8 * g);
    float4 a1 = *(const float4*)(arow + k0 + 8 * g + 4);
    S8u a;
    a.s[0] = f2bf(a0.x); a.s[1] = f2bf(a0.y); a.s[2] = f2bf(a0.z); a.s[3] = f2bf(a0.w);
    a.s[4] = f2bf(a1.x); a.s[5] = f2bf(a1.y); a.s[6] = f2bf(a1.z); a.s[7] = f2bf(a1.w);
#pragma unroll
    for (int nf = 0; nf < 4; ++nf) {
      short8 b = ld16(wt + (size_t)(nf * 16 + c) * EMBED + k0 + 8 * g);
      acc[nf] = __builtin_amdgcn_mfma_f32_16x16x32_bf16(a.v, b, acc[nf], 0, 0, 0);
    }
  }

  // C/D layout: col=lane&15, row=4*(lane>>4)+reg  (m89-verified)
  int row_base = blockIdx.x * 64 + wid * 16 + 4 * g;
#pragma unroll
  for (int nf = 0; nf < 4; ++nf) {
#pragma unroll
    for (int r = 0; r < 4; ++r) {
      int row = row_base + r;
      int col = nf * 16 + c;
      float val = acc[nf][r];
      if (t == 0) {
        qb[(size_t)row * HEAD + col] = f2bf(val * 0.125f);  // fold 1/sqrt(64)
      } else if (t == 1) {
        kb[(size_t)row * HEAD + col] = f2bf(val);
      } else {
        int bb = row >> 12;
        int s = row & (SEQ - 1);
        vt[((size_t)(bb * HEAD + col) << 12) + s] = f2bf(val);  // V transposed
      }
    }
  }
}

// ------- kernel 3: causal flash attention, swapped-QK, 4-way in-block KV split ----
__global__ __launch_bounds__(256) void flash_kernel(
    const ushort* __restrict__ qb, const ushort* __restrict__ kb,
    const ushort* __restrict__ vt, float* __restrict__ out) {
  __shared__ float O_l[4][16][68];   // [wave][query][d], stride 68 keeps 16B align
  __shared__ float m_l[4][16];
  __shared__ float l_l[4][16];

  int tid = threadIdx.x;
  int lane = tid & 63;
  int w = tid >> 6;
  int c = lane & 15;
  int g = lane >> 4;
  int b = blockIdx.x & 3;
  int qt = 255 - (blockIdx.x >> 2);  // longest tiles dispatched first (LPT)
  int q0 = qt << 4;

  const ushort* kbb = kb + (size_t)b * SEQ * HEAD;
  const ushort* vtb = vt + (size_t)b * HEAD * SEQ;

  // Q as B-operand: row = lane&15 = query, contiguous-8 k slots
  const ushort* qrow = qb + (size_t)(b * SEQ + q0 + c) * HEAD + 8 * g;
  short8 qf0 = ld16(qrow);
  short8 qf1 = ld16(qrow + 32);

  f32x4 O[4];
#pragma unroll
  for (int i = 0; i < 4; ++i) O[i] = {0.f, 0.f, 0.f, 0.f};
  float m = -1e30f, l = 0.f;

  int nkt = ((q0 + 15) >> 6) + 1;    // 64-key tiles intersecting the causal band
  for (int kt = w; kt < nkt; kt += 4) {
    int k0 = kt << 6;

    // ---- S^T = K Q^T : lane(c,g) reg r of frag nf = S[key=k0+16nf+4g+r][query=q0+c]
    f32x4 Sf[4];
#pragma unroll
    for (int i = 0; i < 4; ++i) Sf[i] = {0.f, 0.f, 0.f, 0.f};
#pragma unroll
    for (int nf = 0; nf < 4; ++nf) {
      const ushort* krow = kbb + (size_t)(k0 + nf * 16 + c) * HEAD + 8 * g;
      short8 ka0 = ld16(krow);
      short8 ka1 = ld16(krow + 32);
      Sf[nf] = __builtin_amdgcn_mfma_f32_16x16x32_bf16(ka0, qf0, Sf[nf], 0, 0, 0);
      Sf[nf] = __builtin_amdgcn_mfma_f32_16x16x32_bf16(ka1, qf1, Sf[nf], 0, 0, 0);
    }

    // ---- causal mask (uniform branch: only the diagonal tile) ----
    if (k0 + 63 > q0) {
#pragma unroll
      for (int nf = 0; nf < 4; ++nf)
#pragma unroll
        for (int r = 0; r < 4; ++r)
          if (k0 + nf * 16 + 4 * g + r > q0 + c) Sf[nf][r] = -1e30f;
    }

    // ---- online softmax: in-lane 16-max tree + 2 shfl rounds ----
    float x0 = fmaxf(fmaxf(Sf[0][0], Sf[0][1]), fmaxf(Sf[0][2], Sf[0][3]));
    float x1 = fmaxf(fmaxf(Sf[1][0], Sf[1][1]), fmaxf(Sf[1][2], Sf[1][3]));
    float x2 = fmaxf(fmaxf(Sf[2][0], Sf[2][1]), fmaxf(Sf[2][2], Sf[2][3]));
    float x3 = fmaxf(fmaxf(Sf[3][0], Sf[3][1]), fmaxf(Sf[3][2], Sf[3][3]));
    float rm = fmaxf(fmaxf(x0, x1), fmaxf(x2, x3));
    rm = fmaxf(rm, __shfl_xor(rm, 16));
    rm = fmaxf(rm, __shfl_xor(rm, 32));
    rm = fmaxf(rm, m);
    float alpha = __expf(m - rm);
    m = rm;
#pragma unroll
    for (int nf = 0; nf < 4; ++nf)
#pragma unroll
      for (int r = 0; r < 4; ++r)
        Sf[nf][r] = __expf(Sf[nf][r] - m);
    float s0 = (Sf[0][0] + Sf[0][1]) + (Sf[0][2] + Sf[0][3]);
    float s1 = (Sf[1][0] + Sf[1][1]) + (Sf[1][2] + Sf[1][3]);
    float s2 = (Sf[2][0] + Sf[2][1]) + (Sf[2][2] + Sf[2][3]);
    float s3 = (Sf[3][0] + Sf[3][1]) + (Sf[3][2] + Sf[3][3]);
    float rs = (s0 + s1) + (s2 + s3);
    rs += __shfl_xor(rs, 16);
    rs += __shfl_xor(rs, 32);
    l = l * alpha + rs;
#pragma unroll
    for (int nf = 0; nf < 4; ++nf)
#pragma unroll
      for (int r = 0; r < 4; ++r)
        O[nf][r] *= alpha;

    // ---- O^T += V^T P : P is already in B-fragment layout (no LDS, no shuffle) ----
#pragma unroll
    for (int kb2 = 0; kb2 < 2; ++kb2) {
      S8u pa;
#pragma unroll
      for (int r = 0; r < 4; ++r) {
        pa.s[r]     = f2bf(Sf[2 * kb2][r]);
        pa.s[r + 4] = f2bf(Sf[2 * kb2 + 1][r]);
      }
#pragma unroll
      for (int nf = 0; nf < 4; ++nf) {
        // A = V^T rows d=16nf+c, slots use the SAME position->key map as P's landing
        const ushort* vrow = vtb + (size_t)(nf * 16 + c) * SEQ + k0 + 32 * kb2 + 4 * g;
        uint2 vlo = *(const uint2*)vrow;
        uint2 vhi = *(const uint2*)(vrow + 16);
        S8u vb; vb.u[0] = vlo.x; vb.u[1] = vlo.y; vb.u[2] = vhi.x; vb.u[3] = vhi.y;
        O[nf] = __builtin_amdgcn_mfma_f32_16x16x32_bf16(vb.v, pa.v, O[nf], 0, 0, 0);
      }
    }
  }

  // ---- per-wave partials -> LDS ----
#pragma unroll
  for (int nf = 0; nf < 4; ++nf)
    *(f32x4*)&O_l[w][c][nf * 16 + 4 * g] = O[nf];   // O^T[d][q=c] -> O_l[w][q][d]
  if (g == 0) { m_l[w][c] = m; l_l[w][c] = l; }
  __syncthreads();

  // ---- combine 4 KV-split partials, write out ----
  int c2 = tid >> 4;
  int j = tid & 15;
  float mm[4];
  float M = -1e30f;
#pragma unroll
  for (int w2 = 0; w2 < 4; ++w2) { mm[w2] = m_l[w2][c2]; M = fmaxf(M, mm[w2]); }
  float wgt[4];
  float L = 0.f;
#pragma unroll
  for (int w2 = 0; w2 < 4; ++w2) {
    wgt[w2] = __expf(mm[w2] - M);   // no-work waves: exp(-1e30 - M) -> 0
    L += wgt[w2] * l_l[w2][c2];
  }
  f32x4 o = {0.f, 0.f, 0.f, 0.f};
#pragma unroll
  for (int w2 = 0; w2 < 4; ++w2) {
    f32x4 t = *(const f32x4*)&O_l[w2][c2][4 * j];
#pragma unroll
    for (int r = 0; r < 4; ++r) o[r] += wgt[w2] * t[r];
  }
  float inv = 1.0f / L;
  f32x4 res;
#pragma unroll
  for (int r = 0; r < 4; ++r) res[r] = o[r] * inv;
  *(f32x4*)&out[(size_t)(b * SEQ + q0 + c2) * HEAD + 4 * j] = res;
}

extern "C" void kernel_launch(void* const* d_in, const int* in_sizes, int n_in,
                              void* d_out, int out_size, void* d_ws, size_t ws_size,
                              hipStream_t stream) {
  const float* qsrc = (const float*)d_in[0];
  const float* ksrc = (const float*)d_in[1];
  const float* vsrc = (const float*)d_in[2];
  const float* wq = (const float*)d_in[3];
  const float* wk = (const float*)d_in[4];
  const float* wv = (const float*)d_in[5];
  float* out = (float*)d_out;

  char* ws = (char*)d_ws;
  ushort* wT = (ushort*)ws;                           // 384 KB
  ushort* qb = (ushort*)(ws + 393216);                // 2 MB
  ushort* kb = (ushort*)(ws + 393216 + 2097152);      // 2 MB
  ushort* vt = (ushort*)(ws + 393216 + 2 * 2097152);  // 2 MB (transposed V)

  prep_w<<<dim3(768), dim3(256), 0, stream>>>(wq, wk, wv, wT);
  proj_kernel<<<dim3(256, 3), dim3(256), 0, stream>>>(qsrc, ksrc, vsrc, wT, qb, kb, vt);
  flash_kernel<<<dim3(1024), dim3(256), 0, stream>>>(qb, kb, vt, out);
}

// Round 3
// 171.742 us; speedup vs baseline: 1.8181x; 1.0699x over previous
//
#include <hip/hip_runtime.h>

#define EMBED 1024
#define HEAD 64
#define SEQ 4096

typedef __attribute__((ext_vector_type(8))) short short8;
typedef __attribute__((ext_vector_type(4))) float f32x4;

union S8u { short8 v; uint u[4]; ushort s[8]; };

__device__ __forceinline__ ushort f2bf(float f) {
  union { float f; uint u; } x; x.f = f;
  return (ushort)((x.u + 0x7fffu + ((x.u >> 16) & 1u)) >> 16);
}

__device__ __forceinline__ short8 ld16(const ushort* p) {
  uint4 q = *(const uint4*)p;
  S8u t; t.u[0] = q.x; t.u[1] = q.y; t.u[2] = q.z; t.u[3] = q.w;
  return t.v;
}

// ---------------- kernel 1: transpose weights to bf16 wT[t][c][k] ----------------
__global__ __launch_bounds__(256) void prep_w(const float* __restrict__ wq,
                                              const float* __restrict__ wk,
                                              const float* __restrict__ wv,
                                              ushort* __restrict__ wT) {
  int idx = blockIdx.x * 256 + threadIdx.x;
  if (idx >= 3 * HEAD * EMBED) return;
  int t = idx >> 16;            // HEAD*EMBED = 65536
  int rem = idx & 0xFFFF;
  int c = rem >> 10;
  int k = rem & 1023;
  const float* w = (t == 0) ? wq : (t == 1) ? wk : wv;
  wT[idx] = f2bf(w[k * HEAD + c]);
}

// ------ kernel 2: projections -> q_bf16 (scale 0.125*log2e), k_bf16, v^T bf16 -----
__global__ __launch_bounds__(256) void proj_kernel(
    const float* __restrict__ qsrc, const float* __restrict__ ksrc,
    const float* __restrict__ vsrc, const ushort* __restrict__ wT,
    ushort* __restrict__ qb, ushort* __restrict__ kb, ushort* __restrict__ vt) {
  __shared__ ushort vtile[64][72];   // V^T staging (t==2 only), 16B-aligned rows
  int t = blockIdx.y;
  const float* src = (t == 0) ? qsrc : (t == 1) ? ksrc : vsrc;
  const ushort* wt = wT + t * (HEAD * EMBED);
  int lane = threadIdx.x & 63;
  int wid = threadIdx.x >> 6;
  int c = lane & 15;
  int g = lane >> 4;
  int arow_i = blockIdx.x * 64 + wid * 16 + c;   // A row (lane&15)
  const float* arow = src + (size_t)arow_i * EMBED;

  f32x4 acc[4];
#pragma unroll
  for (int i = 0; i < 4; ++i) acc[i] = {0.f, 0.f, 0.f, 0.f};

#pragma unroll 8
  for (int k0 = 0; k0 < EMBED; k0 += 32) {
    // contiguous-8 slot mapping: slot s <-> k0 + 8g + s (same for A and B)
    float4 a0 = *(const float4*)(arow + k0 + 8 * g);
    float4 a1 = *(const float4*)(arow + k0 + 8 * g + 4);
    S8u a;
    a.s[0] = f2bf(a0.x); a.s[1] = f2bf(a0.y); a.s[2] = f2bf(a0.z); a.s[3] = f2bf(a0.w);
    a.s[4] = f2bf(a1.x); a.s[5] = f2bf(a1.y); a.s[6] = f2bf(a1.z); a.s[7] = f2bf(a1.w);
#pragma unroll
    for (int nf = 0; nf < 4; ++nf) {
      short8 b = ld16(wt + (size_t)(nf * 16 + c) * EMBED + k0 + 8 * g);
      acc[nf] = __builtin_amdgcn_mfma_f32_16x16x32_bf16(a.v, b, acc[nf], 0, 0, 0);
    }
  }

  // C/D layout: col=lane&15, row=4*(lane>>4)+reg  (m89-verified)
  if (t == 2) {
    // stage into LDS transposed, then coalesced row writes of V^T
#pragma unroll
    for (int nf = 0; nf < 4; ++nf)
#pragma unroll
      for (int r = 0; r < 4; ++r)
        vtile[nf * 16 + c][wid * 16 + 4 * g + r] = f2bf(acc[nf][r]);
    __syncthreads();
    int d = threadIdx.x >> 2;            // 0..63
    int s0 = (threadIdx.x & 3) << 4;     // 0,16,32,48
    int row0 = blockIdx.x * 64;
    int bb = row0 >> 12;
    int sbase = row0 & (SEQ - 1);
    ushort* dst = vt + ((size_t)(bb * HEAD + d) << 12) + sbase + s0;
    const uint4* srcp = (const uint4*)&vtile[d][s0];
    *(uint4*)dst = srcp[0];
    *(uint4*)(dst + 8) = srcp[1];
  } else {
    int row_base = blockIdx.x * 64 + wid * 16 + 4 * g;
    float scale = (t == 0) ? 0.18033688011112042f : 1.0f;  // 0.125*log2(e) folded into Q
    ushort* dstb = (t == 0) ? qb : kb;
#pragma unroll
    for (int nf = 0; nf < 4; ++nf)
#pragma unroll
      for (int r = 0; r < 4; ++r)
        dstb[(size_t)(row_base + r) * HEAD + nf * 16 + c] = f2bf(acc[nf][r] * scale);
  }
}

// -- kernel 3: causal flash attn, swapped-QK, QBLK=32/wave, 8-wave KV split, XCD-local --
__global__ __launch_bounds__(512, 4) void flash_kernel(
    const ushort* __restrict__ qb, const ushort* __restrict__ kb,
    const ushort* __restrict__ vt, float* __restrict__ out) {
  __shared__ float O_l[8][32][68];
  __shared__ float m_l[8][32];
  __shared__ float l_l[8][32];

  int tid = threadIdx.x;
  int lane = tid & 63;
  int w = tid >> 6;
  int c = lane & 15;
  int g = lane >> 4;

  // XCD-local mapping: bid%8 = XCD slot; batch = slot>>1 (one batch per XCD pair).
  int bid = blockIdx.x;
  int x = bid & 7;
  int b = x >> 1;
  int j = ((bid >> 3) << 1) + (x & 1);   // 0..127
  int qt = 127 - j;                       // LPT: longest first
  int q0 = qt << 5;

  const ushort* kbb = kb + (size_t)b * SEQ * HEAD;
  const ushort* vtb = vt + (size_t)b * HEAD * SEQ;

  // Q as B-operand: query = 16*qf + (lane&15), contiguous-8 k slots (pre-scaled)
  short8 qa[2][2];
#pragma unroll
  for (int qf = 0; qf < 2; ++qf) {
    const ushort* qrow = qb + (size_t)(b * SEQ + q0 + 16 * qf + c) * HEAD + 8 * g;
    qa[qf][0] = ld16(qrow);
    qa[qf][1] = ld16(qrow + 32);
  }

  f32x4 O[4][2];
#pragma unroll
  for (int i = 0; i < 4; ++i)
#pragma unroll
    for (int qf = 0; qf < 2; ++qf) O[i][qf] = {0.f, 0.f, 0.f, 0.f};
  float m[2] = {-1e30f, -1e30f};
  float l[2] = {0.f, 0.f};

  int nkt = ((q0 + 31) >> 6) + 1;   // 64-key tiles intersecting the causal band
  for (int kt = w; kt < nkt; kt += 8) {
    int k0 = kt << 6;

    // ---- V loads issued first: latency hides under QK + softmax ----
    S8u vb[2][4];
#pragma unroll
    for (int sl = 0; sl < 2; ++sl)
#pragma unroll
      for (int nf = 0; nf < 4; ++nf) {
        const ushort* vrow = vtb + (size_t)(nf * 16 + c) * SEQ + k0 + 32 * sl + 4 * g;
        uint2 vlo = *(const uint2*)vrow;
        uint2 vhi = *(const uint2*)(vrow + 16);
        vb[sl][nf].u[0] = vlo.x; vb[sl][nf].u[1] = vlo.y;
        vb[sl][nf].u[2] = vhi.x; vb[sl][nf].u[3] = vhi.y;
      }

    // ---- S^T = K Q^T : frag [nf][qf]: key = k0+16nf+4g+r, query = q0+16qf+c ----
    f32x4 Sf[4][2];
#pragma unroll
    for (int i = 0; i < 4; ++i)
#pragma unroll
      for (int qf = 0; qf < 2; ++qf) Sf[i][qf] = {0.f, 0.f, 0.f, 0.f};
#pragma unroll
    for (int nf = 0; nf < 4; ++nf) {
      const ushort* krow = kbb + (size_t)(k0 + nf * 16 + c) * HEAD + 8 * g;
      short8 ka0 = ld16(krow);
      short8 ka1 = ld16(krow + 32);
#pragma unroll
      for (int qf = 0; qf < 2; ++qf) {
        Sf[nf][qf] = __builtin_amdgcn_mfma_f32_16x16x32_bf16(ka0, qa[qf][0], Sf[nf][qf], 0, 0, 0);
        Sf[nf][qf] = __builtin_amdgcn_mfma_f32_16x16x32_bf16(ka1, qa[qf][1], Sf[nf][qf], 0, 0, 0);
      }
    }

    // ---- causal mask (only tiles crossing the diagonal) ----
    if (k0 + 63 > q0) {
#pragma unroll
      for (int nf = 0; nf < 4; ++nf)
#pragma unroll
        for (int qf = 0; qf < 2; ++qf)
#pragma unroll
          for (int r = 0; r < 4; ++r)
            if (k0 + nf * 16 + 4 * g + r > q0 + 16 * qf + c) Sf[nf][qf][r] = -1e30f;
    }

    // ---- online softmax per q-frag (exp2 domain; log2e folded into Q) ----
#pragma unroll
    for (int qf = 0; qf < 2; ++qf) {
      float x0 = fmaxf(fmaxf(Sf[0][qf][0], Sf[0][qf][1]), fmaxf(Sf[0][qf][2], Sf[0][qf][3]));
      float x1 = fmaxf(fmaxf(Sf[1][qf][0], Sf[1][qf][1]), fmaxf(Sf[1][qf][2], Sf[1][qf][3]));
      float x2 = fmaxf(fmaxf(Sf[2][qf][0], Sf[2][qf][1]), fmaxf(Sf[2][qf][2], Sf[2][qf][3]));
      float x3 = fmaxf(fmaxf(Sf[3][qf][0], Sf[3][qf][1]), fmaxf(Sf[3][qf][2], Sf[3][qf][3]));
      float rm = fmaxf(fmaxf(x0, x1), fmaxf(x2, x3));
      rm = fmaxf(rm, __shfl_xor(rm, 16));
      rm = fmaxf(rm, __shfl_xor(rm, 32));
      rm = fmaxf(rm, m[qf]);
      float alpha = exp2f(m[qf] - rm);
      m[qf] = rm;
#pragma unroll
      for (int nf = 0; nf < 4; ++nf)
#pragma unroll
        for (int r = 0; r < 4; ++r)
          Sf[nf][qf][r] = exp2f(Sf[nf][qf][r] - rm);
      float s0 = (Sf[0][qf][0] + Sf[0][qf][1]) + (Sf[0][qf][2] + Sf[0][qf][3]);
      float s1 = (Sf[1][qf][0] + Sf[1][qf][1]) + (Sf[1][qf][2] + Sf[1][qf][3]);
      float s2 = (Sf[2][qf][0] + Sf[2][qf][1]) + (Sf[2][qf][2] + Sf[2][qf][3]);
      float s3 = (Sf[3][qf][0] + Sf[3][qf][1]) + (Sf[3][qf][2] + Sf[3][qf][3]);
      float rs = (s0 + s1) + (s2 + s3);
      rs += __shfl_xor(rs, 16);
      rs += __shfl_xor(rs, 32);
      l[qf] = l[qf] * alpha + rs;
#pragma unroll
      for (int nf = 0; nf < 4; ++nf)
#pragma unroll
        for (int r = 0; r < 4; ++r)
          O[nf][qf][r] *= alpha;
    }

    // ---- O^T += V^T P : P already in B-fragment layout ----
#pragma unroll
    for (int qf = 0; qf < 2; ++qf)
#pragma unroll
      for (int sl = 0; sl < 2; ++sl) {
        S8u pa;
#pragma unroll
        for (int r = 0; r < 4; ++r) {
          pa.s[r]     = f2bf(Sf[2 * sl][qf][r]);
          pa.s[r + 4] = f2bf(Sf[2 * sl + 1][qf][r]);
        }
#pragma unroll
        for (int nf = 0; nf < 4; ++nf)
          O[nf][qf] = __builtin_amdgcn_mfma_f32_16x16x32_bf16(vb[sl][nf].v, pa.v, O[nf][qf], 0, 0, 0);
      }
  }

  // ---- per-wave partials -> LDS ----
#pragma unroll
  for (int nf = 0; nf < 4; ++nf)
#pragma unroll
    for (int qf = 0; qf < 2; ++qf)
      *(f32x4*)&O_l[w][16 * qf + c][16 * nf + 4 * g] = O[nf][qf];
  if (g == 0) {
#pragma unroll
    for (int qf = 0; qf < 2; ++qf) {
      m_l[w][16 * qf + c] = m[qf];
      l_l[w][16 * qf + c] = l[qf];
    }
  }
  __syncthreads();

  // ---- combine 8 KV-split partials (512 thr = 32 q x 16 d-quads) ----
  int q = tid >> 4;
  int jj = tid & 15;
  float mm[8];
  float M = -1e30f;
#pragma unroll
  for (int w2 = 0; w2 < 8; ++w2) { mm[w2] = m_l[w2][q]; M = fmaxf(M, mm[w2]); }
  float wgt[8];
  float L = 0.f;
#pragma unroll
  for (int w2 = 0; w2 < 8; ++w2) {
    wgt[w2] = exp2f(mm[w2] - M);   // idle waves: exp2(-1e30 - M) -> 0
    L += wgt[w2] * l_l[w2][q];
  }
  f32x4 o = {0.f, 0.f, 0.f, 0.f};
#pragma unroll
  for (int w2 = 0; w2 < 8; ++w2) {
    f32x4 t = *(const f32x4*)&O_l[w2][q][4 * jj];
#pragma unroll
    for (int r = 0; r < 4; ++r) o[r] += wgt[w2] * t[r];
  }
  float inv = 1.0f / L;
  f32x4 res;
#pragma unroll
  for (int r = 0; r < 4; ++r) res[r] = o[r] * inv;
  *(f32x4*)&out[(size_t)(b * SEQ + q0 + q) * HEAD + 4 * jj] = res;
}

extern "C" void kernel_launch(void* const* d_in, const int* in_sizes, int n_in,
                              void* d_out, int out_size, void* d_ws, size_t ws_size,
                              hipStream_t stream) {
  const float* qsrc = (const float*)d_in[0];
  const float* ksrc = (const float*)d_in[1];
  const float* vsrc = (const float*)d_in[2];
  const float* wq = (const float*)d_in[3];
  const float* wk = (const float*)d_in[4];
  const float* wv = (const float*)d_in[5];
  float* out = (float*)d_out;

  char* ws = (char*)d_ws;
  ushort* wT = (ushort*)ws;                           // 384 KB
  ushort* qb = (ushort*)(ws + 393216);                // 2 MB
  ushort* kb = (ushort*)(ws + 393216 + 2097152);      // 2 MB
  ushort* vt = (ushort*)(ws + 393216 + 2 * 2097152);  // 2 MB (transposed V)

  prep_w<<<dim3(768), dim3(256), 0, stream>>>(wq, wk, wv, wT);
  proj_kernel<<<dim3(256, 3), dim3(256), 0, stream>>>(qsrc, ksrc, vsrc, wT, qb, kb, vt);
  flash_kernel<<<dim3(512), dim3(512), 0, stream>>>(qb, kb, vt, out);
}

// Round 5
// 170.463 us; speedup vs baseline: 1.8317x; 1.0075x over previous
//
#include <hip/hip_runtime.h>

#define EMBED 1024
#define HEAD 64
#define SEQ 4096

typedef __attribute__((ext_vector_type(8))) short short8;
typedef __attribute__((ext_vector_type(4))) float f32x4;

union S8u { short8 v; uint u[4]; ushort s[8]; };

__device__ __forceinline__ ushort f2bf(float f) {
  union { float f; uint u; } x; x.f = f;
  return (ushort)((x.u + 0x7fffu + ((x.u >> 16) & 1u)) >> 16);
}

__device__ __forceinline__ short8 ld16(const ushort* p) {
  uint4 q = *(const uint4*)p;
  S8u t; t.u[0] = q.x; t.u[1] = q.y; t.u[2] = q.z; t.u[3] = q.w;
  return t.v;
}

// ---------------- kernel 1: transpose weights to bf16 wT[t][c][k] ----------------
__global__ __launch_bounds__(256) void prep_w(const float* __restrict__ wq,
                                              const float* __restrict__ wk,
                                              const float* __restrict__ wv,
                                              ushort* __restrict__ wT) {
  int idx = blockIdx.x * 256 + threadIdx.x;
  if (idx >= 3 * HEAD * EMBED) return;
  int t = idx >> 16;
  int rem = idx & 0xFFFF;
  int c = rem >> 10;
  int k = rem & 1023;
  const float* w = (t == 0) ? wq : (t == 1) ? wk : wv;
  wT[idx] = f2bf(w[k * HEAD + c]);
}

// ------ kernel 2: projections -> q_bf16 (scale 0.125*log2e), k_bf16, v^T bf16 -----
__global__ __launch_bounds__(256) void proj_kernel(
    const float* __restrict__ qsrc, const float* __restrict__ ksrc,
    const float* __restrict__ vsrc, const ushort* __restrict__ wT,
    ushort* __restrict__ qb, ushort* __restrict__ kb, ushort* __restrict__ vt) {
  __shared__ ushort vtile[64][72];
  int t = blockIdx.y;
  const float* src = (t == 0) ? qsrc : (t == 1) ? ksrc : vsrc;
  const ushort* wt = wT + t * (HEAD * EMBED);
  int lane = threadIdx.x & 63;
  int wid = threadIdx.x >> 6;
  int c = lane & 15;
  int g = lane >> 4;
  int arow_i = blockIdx.x * 64 + wid * 16 + c;
  const float* arow = src + (size_t)arow_i * EMBED;

  f32x4 acc[4];
#pragma unroll
  for (int i = 0; i < 4; ++i) acc[i] = {0.f, 0.f, 0.f, 0.f};

#pragma unroll 8
  for (int k0 = 0; k0 < EMBED; k0 += 32) {
    float4 a0 = *(const float4*)(arow + k0 + 8 * g);
    float4 a1 = *(const float4*)(arow + k0 + 8 * g + 4);
    S8u a;
    a.s[0] = f2bf(a0.x); a.s[1] = f2bf(a0.y); a.s[2] = f2bf(a0.z); a.s[3] = f2bf(a0.w);
    a.s[4] = f2bf(a1.x); a.s[5] = f2bf(a1.y); a.s[6] = f2bf(a1.z); a.s[7] = f2bf(a1.w);
#pragma unroll
    for (int nf = 0; nf < 4; ++nf) {
      short8 b = ld16(wt + (size_t)(nf * 16 + c) * EMBED + k0 + 8 * g);
      acc[nf] = __builtin_amdgcn_mfma_f32_16x16x32_bf16(a.v, b, acc[nf], 0, 0, 0);
    }
  }

  if (t == 2) {
#pragma unroll
    for (int nf = 0; nf < 4; ++nf)
#pragma unroll
      for (int r = 0; r < 4; ++r)
        vtile[nf * 16 + c][wid * 16 + 4 * g + r] = f2bf(acc[nf][r]);
    __syncthreads();
    int d = threadIdx.x >> 2;
    int s0 = (threadIdx.x & 3) << 4;
    int row0 = blockIdx.x * 64;
    int bb = row0 >> 12;
    int sbase = row0 & (SEQ - 1);
    ushort* dst = vt + ((size_t)(bb * HEAD + d) << 12) + sbase + s0;
    const uint4* srcp = (const uint4*)&vtile[d][s0];
    *(uint4*)dst = srcp[0];
    *(uint4*)(dst + 8) = srcp[1];
  } else {
    int row_base = blockIdx.x * 64 + wid * 16 + 4 * g;
    float scale = (t == 0) ? 0.18033688011112042f : 1.0f;  // 0.125*log2(e)
    ushort* dstb = (t == 0) ? qb : kb;
#pragma unroll
    for (int nf = 0; nf < 4; ++nf)
#pragma unroll
      for (int r = 0; r < 4; ++r)
        dstb[(size_t)(row_base + r) * HEAD + nf * 16 + c] = f2bf(acc[nf][r] * scale);
  }
}

// ---- kernel 3: flash attn — 8 waves = 2 qw x 4 kw, LDS-staged KV, in-block merge ----
__global__ __launch_bounds__(512, 2) void flash_kernel(
    const ushort* __restrict__ qb, const ushort* __restrict__ kb,
    const ushort* __restrict__ vt, float* __restrict__ out) {
  __shared__ __align__(16) char smem[65536];  // 4 K tiles @0, 4 V tiles @32768; aliased as O_l
  __shared__ float ml[8][32][2];

  const int tid = threadIdx.x;
  const int lane = tid & 63;
  const int w = tid >> 6;
  const int qw = w & 1, kw = w >> 1;
  const int c = lane & 15, g = lane >> 4;

  const int bid = blockIdx.x;
  const int b = bid & 3;
  const int sb = 63 - (bid >> 2);        // LPT: longest first
  const int R = (sb + 4) >> 2;           // staging rounds of 4 tiles
  const int q0w = sb * 64 + qw * 32;

  const char* kbase = (const char*)(kb + (size_t)b * SEQ * HEAD);
  const char* vbase = (const char*)(vt + (size_t)b * HEAD * SEQ);

  // staging: thread covers row srow, 16B chunk (tid&7) of each 64x128B tile
  const int srow = tid >> 3;
  const int scol = (tid & 7) << 4;
  const int sdst = srow * 128 + (scol ^ ((srow & 7) << 4));   // XOR-swizzled dest
  const char* kgp = kbase + tid * 16;
  const char* vgp = vbase + srow * 8192 + scol;

  // Q fragments (query = q0w + 16qf + c), pre-scaled by 0.125*log2e
  short8 qa[2][2];
#pragma unroll
  for (int qf = 0; qf < 2; ++qf) {
    const ushort* qrow = qb + (size_t)(b * SEQ + q0w + 16 * qf + c) * HEAD + 8 * g;
    qa[qf][0] = ld16(qrow);
    qa[qf][1] = ld16(qrow + 32);
  }

  f32x4 O[4][2];
#pragma unroll
  for (int i = 0; i < 4; ++i)
#pragma unroll
    for (int qf = 0; qf < 2; ++qf) O[i][qf] = {0.f, 0.f, 0.f, 0.f};
  float m[2] = {-1e30f, -1e30f};
  float l[2] = {0.f, 0.f};

  // prologue: loads for round 0
  uint4 sK[4], sV[4];
#pragma unroll
  for (int tt = 0; tt < 4; ++tt) {
    sK[tt] = *(const uint4*)(kgp + tt * 8192);
    sV[tt] = *(const uint4*)(vgp + tt * 128);
  }

  const int kfb = kw * 8192;             // this wave's K tile base in LDS
  const int vfb = 32768 + kw * 8192;     // this wave's V tile base in LDS

  for (int r = 0; r < R; ++r) {
    // ---- write staged regs to LDS ----
#pragma unroll
    for (int tt = 0; tt < 4; ++tt) {
      *(uint4*)(smem + tt * 8192 + sdst) = sK[tt];
      *(uint4*)(smem + 32768 + tt * 8192 + sdst) = sV[tt];
    }
    __syncthreads();

    // ---- issue next round's global loads (hidden under compute) ----
    if (r + 1 < R) {
      kgp += 32768; vgp += 512;
#pragma unroll
      for (int tt = 0; tt < 4; ++tt) {
        sK[tt] = *(const uint4*)(kgp + tt * 8192);
        sV[tt] = *(const uint4*)(vgp + tt * 128);
      }
    }

    // ---- compute this wave's tile ----
    int kt = 4 * r + kw;
    if (kt <= sb) {
      int k0 = kt << 6;

      // S^T = K Q^T : frag [nf][qf] reg rr : key = k0+16nf+4g+rr, query = q0w+16qf+c
      f32x4 Sf[4][2];
#pragma unroll
      for (int i = 0; i < 4; ++i)
#pragma unroll
        for (int qf = 0; qf < 2; ++qf) Sf[i][qf] = {0.f, 0.f, 0.f, 0.f};
#pragma unroll
      for (int nf = 0; nf < 4; ++nf) {
        int row = 16 * nf + c;
        int sw = (row & 7) << 4;
        uint4 kv = *(const uint4*)(smem + kfb + row * 128 + ((16 * g) ^ sw));
        S8u ka0;
        ka0.u[0] = kv.x; ka0.u[1] = kv.y; ka0.u[2] = kv.z; ka0.u[3] = kv.w;
#pragma unroll
        for (int qf = 0; qf < 2; ++qf)
          Sf[nf][qf] = __builtin_amdgcn_mfma_f32_16x16x32_bf16(ka0.v, qa[qf][0], Sf[nf][qf], 0, 0, 0);
        uint4 kv2 = *(const uint4*)(smem + kfb + row * 128 + ((64 + 16 * g) ^ sw));
        S8u ka1;
        ka1.u[0] = kv2.x; ka1.u[1] = kv2.y; ka1.u[2] = kv2.z; ka1.u[3] = kv2.w;
#pragma unroll
        for (int qf = 0; qf < 2; ++qf)
          Sf[nf][qf] = __builtin_amdgcn_mfma_f32_16x16x32_bf16(ka1.v, qa[qf][1], Sf[nf][qf], 0, 0, 0);
      }

      // causal mask: only the diagonal tile
      if (kt == sb) {
#pragma unroll
        for (int nf = 0; nf < 4; ++nf)
#pragma unroll
          for (int qf = 0; qf < 2; ++qf)
#pragma unroll
            for (int rr = 0; rr < 4; ++rr)
              if (k0 + nf * 16 + 4 * g + rr > q0w + 16 * qf + c) Sf[nf][qf][rr] = -1e30f;
      }

      // ---- online softmax (exp2 domain), per-tile rescale (round-3-proven) ----
#pragma unroll
      for (int qf = 0; qf < 2; ++qf) {
        float x0 = fmaxf(fmaxf(Sf[0][qf][0], Sf[0][qf][1]), fmaxf(Sf[0][qf][2], Sf[0][qf][3]));
        float x1 = fmaxf(fmaxf(Sf[1][qf][0], Sf[1][qf][1]), fmaxf(Sf[1][qf][2], Sf[1][qf][3]));
        float x2 = fmaxf(fmaxf(Sf[2][qf][0], Sf[2][qf][1]), fmaxf(Sf[2][qf][2], Sf[2][qf][3]));
        float x3 = fmaxf(fmaxf(Sf[3][qf][0], Sf[3][qf][1]), fmaxf(Sf[3][qf][2], Sf[3][qf][3]));
        float rm = fmaxf(fmaxf(x0, x1), fmaxf(x2, x3));
        rm = fmaxf(rm, __shfl_xor(rm, 16));
        rm = fmaxf(rm, __shfl_xor(rm, 32));
        rm = fmaxf(rm, m[qf]);
        float alpha = exp2f(m[qf] - rm);
        m[qf] = rm;
#pragma unroll
        for (int nf = 0; nf < 4; ++nf)
#pragma unroll
          for (int rr = 0; rr < 4; ++rr)
            Sf[nf][qf][rr] = exp2f(Sf[nf][qf][rr] - rm);
        float s0 = (Sf[0][qf][0] + Sf[0][qf][1]) + (Sf[0][qf][2] + Sf[0][qf][3]);
        float s1 = (Sf[1][qf][0] + Sf[1][qf][1]) + (Sf[1][qf][2] + Sf[1][qf][3]);
        float s2 = (Sf[2][qf][0] + Sf[2][qf][1]) + (Sf[2][qf][2] + Sf[2][qf][3]);
        float s3 = (Sf[3][qf][0] + Sf[3][qf][1]) + (Sf[3][qf][2] + Sf[3][qf][3]);
        float rs = (s0 + s1) + (s2 + s3);
        rs += __shfl_xor(rs, 16);
        rs += __shfl_xor(rs, 32);
        l[qf] = l[qf] * alpha + rs;
#pragma unroll
        for (int nf = 0; nf < 4; ++nf)
#pragma unroll
          for (int rr = 0; rr < 4; ++rr)
            O[nf][qf][rr] *= alpha;

        // ---- O^T += V^T P : P already in B-fragment layout (f2bf, round-3-proven) ----
#pragma unroll
        for (int sl = 0; sl < 2; ++sl) {
          S8u pa;
#pragma unroll
          for (int rr = 0; rr < 4; ++rr) {
            pa.s[rr]     = f2bf(Sf[2 * sl][qf][rr]);
            pa.s[rr + 4] = f2bf(Sf[2 * sl + 1][qf][rr]);
          }
#pragma unroll
          for (int nf = 0; nf < 4; ++nf) {
            int row = 16 * nf + c;
            int sw = (row & 7) << 4;
            S8u vbf;
            uint2 lo = *(const uint2*)(smem + vfb + row * 128 + ((64 * sl + 8 * g) ^ sw));
            uint2 hi = *(const uint2*)(smem + vfb + row * 128 + ((64 * sl + 32 + 8 * g) ^ sw));
            vbf.u[0] = lo.x; vbf.u[1] = lo.y; vbf.u[2] = hi.x; vbf.u[3] = hi.y;
            O[nf][qf] = __builtin_amdgcn_mfma_f32_16x16x32_bf16(vbf.v, pa.v, O[nf][qf], 0, 0, 0);
          }
        }
      }
    }
    __syncthreads();
  }

  // ---- partials -> LDS (alias staging buffer; all compute done) ----
  float* O_l = (float*)smem;   // [8][32][64]
#pragma unroll
  for (int nf = 0; nf < 4; ++nf)
#pragma unroll
    for (int qf = 0; qf < 2; ++qf)
      *(f32x4*)(O_l + ((w * 32 + 16 * qf + c) * 64 + 16 * nf + 4 * g)) = O[nf][qf];
  if (g == 0) {
#pragma unroll
    for (int qf = 0; qf < 2; ++qf) {
      ml[w][16 * qf + c][0] = m[qf];
      ml[w][16 * qf + c][1] = l[qf];
    }
  }
  __syncthreads();

  // ---- merge 4 kv-split partials per q-block; 1024 outputs = 2 per thread ----
#pragma unroll
  for (int rep = 0; rep < 2; ++rep) {
    int i = tid + rep * 512;
    int qw2 = i >> 9;
    int q = (i >> 4) & 31;
    int dq = i & 15;
    float mm[4], M = -1e30f;
#pragma unroll
    for (int k2 = 0; k2 < 4; ++k2) { mm[k2] = ml[2 * k2 + qw2][q][0]; M = fmaxf(M, mm[k2]); }
    float wgt[4], L = 0.f;
#pragma unroll
    for (int k2 = 0; k2 < 4; ++k2) {
      wgt[k2] = exp2f(mm[k2] - M);   // idle waves: exp2(-1e30 - M) -> 0
      L += wgt[k2] * ml[2 * k2 + qw2][q][1];
    }
    f32x4 acc = {0.f, 0.f, 0.f, 0.f};
#pragma unroll
    for (int k2 = 0; k2 < 4; ++k2) {
      f32x4 t = *(const f32x4*)(O_l + (((2 * k2 + qw2) * 32 + q) * 64 + 4 * dq));
#pragma unroll
      for (int rr = 0; rr < 4; ++rr) acc[rr] += wgt[k2] * t[rr];
    }
    float inv = 1.0f / L;
    f32x4 res;
#pragma unroll
    for (int rr = 0; rr < 4; ++rr) res[rr] = acc[rr] * inv;
    *(f32x4*)&out[(size_t)(b * SEQ + sb * 64 + qw2 * 32 + q) * HEAD + 4 * dq] = res;
  }
}

extern "C" void kernel_launch(void* const* d_in, const int* in_sizes, int n_in,
                              void* d_out, int out_size, void* d_ws, size_t ws_size,
                              hipStream_t stream) {
  const float* qsrc = (const float*)d_in[0];
  const float* ksrc = (const float*)d_in[1];
  const float* vsrc = (const float*)d_in[2];
  const float* wq = (const float*)d_in[3];
  const float* wk = (const float*)d_in[4];
  const float* wv = (const float*)d_in[5];
  float* out = (float*)d_out;

  char* ws = (char*)d_ws;
  ushort* wT = (ushort*)ws;                           // 384 KB
  ushort* qb = (ushort*)(ws + 393216);                // 2 MB
  ushort* kb = (ushort*)(ws + 393216 + 2097152);      // 2 MB
  ushort* vt = (ushort*)(ws + 393216 + 2 * 2097152);  // 2 MB (transposed V)

  prep_w<<<dim3(768), dim3(256), 0, stream>>>(wq, wk, wv, wT);
  proj_kernel<<<dim3(256, 3), dim3(256), 0, stream>>>(qsrc, ksrc, vsrc, wT, qb, kb, vt);
  flash_kernel<<<dim3(256), dim3(512), 0, stream>>>(qb, kb, vt, out);
}